// Round 12
// baseline (1761.859 us; speedup 1.0000x reference)
//
#include <hip/hip_runtime.h>
#include <hip/hip_bf16.h>
#include <cstdint>
#include <cstddef>

typedef unsigned short u16;
typedef __attribute__((ext_vector_type(4))) float f32x4;
typedef __attribute__((ext_vector_type(8))) short short8;

#define B_SZ 256
#define T_SZ 256
#define IN_SZ 64
#define H_SZ 512
#define G3 1536
#define BHE (256 * 512)   // elements per ring slot

__device__ __forceinline__ u16 f2bf(float f) {
  union { float f; unsigned int i; } v; v.f = f;
  unsigned int x = v.i;
  unsigned int r = (x + 0x7fffu + ((x >> 16) & 1u)) >> 16;  // RNE
  return (u16)r;
}
__device__ __forceinline__ float sigmoidf_(float x) { return 1.0f / (1.0f + __expf(-x)); }
__device__ __forceinline__ float tanhf_(float x) {
  float e = __expf(-2.0f * x); return (1.0f - e) / (1.0f + e);
}

// ---- flag primitives (R10-proven dual mechanism) ----
// Publish: plain store -> shared XCD L2 (L1 write-through), then sc1 atomic
// (R4/R5-proven L3 path). Same monotone value -> any interleaving safe.
__device__ __forceinline__ void st_flag_dual(int* p, int v) {
  asm volatile("global_store_dword %0, %1, off" :: "v"(p), "v"(v) : "memory");
  __hip_atomic_store(p, v, __ATOMIC_RELAXED, __HIP_MEMORY_SCOPE_AGENT);
}
// Poll fast path: L1-inv + plain load + waitcnt fused in ONE asm (rule #18).
__device__ __forceinline__ int ld_flag_fast(const int* p) {
  int v;
  asm volatile("buffer_inv sc0\n\t"
               "global_load_dword %0, %1, off\n\t"
               "s_waitcnt vmcnt(0)"
               : "=v"(v) : "v"(p) : "memory");
  return v;
}

// ---------------- weight-norm + bf16 cast: one wave per row ----------------
__global__ __launch_bounds__(256)
void norm_cast_kernel(const float* __restrict__ v, const float* __restrict__ g,
                      u16* __restrict__ out, int cols) {
  int row = blockIdx.x * 4 + (threadIdx.x >> 6);
  int lane = threadIdx.x & 63;
  const float* vr = v + (size_t)row * cols;
  float s = 0.f;
  for (int c = lane; c < cols; c += 64) { float t = vr[c]; s += t * t; }
  for (int o = 32; o; o >>= 1) s += __shfl_xor(s, o);
  float scale = g[row] / sqrtf(s);
  for (int c = lane; c < cols; c += 64) out[(size_t)row * cols + c] = f2bf(vr[c] * scale);
}

__global__ __launch_bounds__(256)
void castx_kernel(const float* __restrict__ x, u16* __restrict__ xb) {
  int i = blockIdx.x * 256 + threadIdx.x;
  float4 v = ((const float4*)x)[i];
  ushort4 o;
  o.x = f2bf(v.x); o.y = f2bf(v.y); o.z = f2bf(v.z); o.w = f2bf(v.w);
  ((ushort4*)xb)[i] = o;
}

// ------------- fused 2-layer GRU: both layers in one block, 1 flag/step -----
// R11 structure (passed, 5.7us/step), flags switched to L2 fast path + L3
// fallback. 256 blocks x 256 thr, 1 blk/CU. g = batch group (16 rows),
// s = hidden slice (32 units); waves: wv&1 = unit-tile, wv>>1 = layer role.
// Step t: L0 computes h0(t) from h0(t-1); L1 computes h1(t-1) from h0(t-1),
// h1(t-2) -- all inputs from rendezvous t-1 => ONE flag per block per step,
// wave0-only poll. Depth-4 rings; WAR implied (writer at t+4 saw t+3 done).
__global__ __launch_bounds__(256, 1)
void fused_rnn_kernel(const u16* __restrict__ whh0c, const u16* __restrict__ wih0c,
                      const u16* __restrict__ whh1c, const u16* __restrict__ wih1c,
                      const float* __restrict__ bih0, const float* __restrict__ bhh0,
                      const float* __restrict__ bih1, const float* __restrict__ bhh1,
                      const u16* __restrict__ xb, u16* __restrict__ h0ring,
                      u16* __restrict__ h1ring, float* __restrict__ h1fin,
                      int* __restrict__ flags, int* __restrict__ claim) {
  __shared__ u16 Wx1[96 * 512];   // Wih1 slice (3x32 gate rows x 512), swizzled
  __shared__ int role_sh;

  const int tid = threadIdx.x;
  if (tid == 0) {
    int xcd;
    asm volatile("s_getreg_b32 %0, hwreg(HW_REG_XCC_ID)" : "=s"(xcd));
    xcd &= 7;
    role_sh = xcd * 64 + atomicAdd(&claim[xcd], 1);
  }
  __syncthreads();
  const int r = role_sh & 63;
  if (r >= 32) return;               // can't happen (pigeonhole 32/XCD)
  const int g = (role_sh >> 6) * 2 + (r & 1);   // batch group (16 rows)
  const int s = r >> 1;              // hidden slice (32 units)

  const int lane = tid & 63;
  const int wv = tid >> 6;
  const int u16i = wv & 1;           // unit-tile within slice
  const int isL1 = wv >> 1;          // layer role
  const int l15 = lane & 15;
  const int q = lane >> 4;
  const int ul = u16i * 16 + l15;    // local unit 0..31
  const int gu = s * 32 + ul;        // global unit
  const int swz = (ul & 7) << 4;
  const size_t arow = (size_t)(g * 16 + l15) * 512;   // A-row base in rings

  // stage Wih1 slice swizzled into LDS
  for (int idx = tid; idx < 6144; idx += 256) {
    int rr = idx >> 6, c16 = idx & 63;
    int grow = (rr >> 5) * 512 + s * 32 + (rr & 31);
    int sb = (c16 << 4) ^ ((rr & 7) << 4);
    uint4 vv = *(const uint4*)((const char*)wih1c + (size_t)grow * 1024 + sb);
    *(uint4*)((char*)Wx1 + rr * 1024 + (c16 << 4)) = vv;
  }

  // Whh fragments -> registers (48 x short8), per layer role
  const u16* whhp = isL1 ? whh1c : whh0c;
  short8 whf[3][16];
  #pragma unroll
  for (int g3 = 0; g3 < 3; ++g3)
    #pragma unroll
    for (int kk = 0; kk < 16; ++kk)
      whf[g3][kk] = *(const short8*)(whhp + (size_t)(g3 * 512 + gu) * 512 + kk * 32 + q * 8);
  // L0: Wih0 fragments
  short8 wxf[3][2];
  if (!isL1) {
    #pragma unroll
    for (int g3 = 0; g3 < 3; ++g3)
      #pragma unroll
      for (int k2 = 0; k2 < 2; ++k2)
        wxf[g3][k2] = *(const short8*)(wih0c + (size_t)(g3 * 512 + gu) * 64 + k2 * 32 + q * 8);
  }
  const float* bi = isL1 ? bih1 : bih0;
  const float* bh = isL1 ? bhh1 : bhh0;
  const float bi_r = bi[gu], bi_z = bi[512 + gu], bi_n = bi[1024 + gu];
  const float bh_r = bh[gu], bh_z = bh[512 + gu], bh_n = bh[1024 + gu];

  __syncthreads();   // staging visible

  int* gf = flags + g * 64;          // this group's 16 flags (one 64B line)
  float h_old[4] = {0.f, 0.f, 0.f, 0.f};

  for (int t = 0; t <= T_SZ; ++t) {
    if (t > 0) {
      __syncthreads();               // all 4 waves' step t-1 publishes drained
      if (wv == 0) {
        if (lane == 0) st_flag_dual(&gf[s], t);
        int* p = gf + l15;           // 64 lanes poll 16 flags (4x dup)
        int cap = 0;
        while (true) {
          int f = ld_flag_fast(p);   // L2 fast path
          if (__all(f >= t)) break;
          if ((cap & 7) == 7) {      // R5-proven L3 fallback
            f = __hip_atomic_load(p, __ATOMIC_RELAXED, __HIP_MEMORY_SCOPE_AGENT);
            if (__all(f >= t)) break;
          }
          __builtin_amdgcn_s_sleep(1);
          if (++cap > 200000) break; // hang breaker; never hit in normal runs
        }
        __builtin_amdgcn_sched_barrier(0);
      }
      __syncthreads();               // release all waves
      asm volatile("buffer_inv sc0" ::: "memory");   // once per step
    }
    if (!isL1) {
      if (t < T_SZ) {
        f32x4 accr = {0.f,0.f,0.f,0.f}, accz = {0.f,0.f,0.f,0.f};
        f32x4 axn  = {0.f,0.f,0.f,0.f}, ahn  = {0.f,0.f,0.f,0.f};
        const u16* xp = xb + ((size_t)(g * 16 + l15) * T_SZ + t) * 64;
        short8 ax0 = *(const short8*)(xp + q * 8);
        short8 ax1 = *(const short8*)(xp + 32 + q * 8);
        accr = __builtin_amdgcn_mfma_f32_16x16x32_bf16(ax0, wxf[0][0], accr, 0, 0, 0);
        accz = __builtin_amdgcn_mfma_f32_16x16x32_bf16(ax0, wxf[1][0], accz, 0, 0, 0);
        axn  = __builtin_amdgcn_mfma_f32_16x16x32_bf16(ax0, wxf[2][0], axn, 0, 0, 0);
        accr = __builtin_amdgcn_mfma_f32_16x16x32_bf16(ax1, wxf[0][1], accr, 0, 0, 0);
        accz = __builtin_amdgcn_mfma_f32_16x16x32_bf16(ax1, wxf[1][1], accz, 0, 0, 0);
        axn  = __builtin_amdgcn_mfma_f32_16x16x32_bf16(ax1, wxf[2][1], axn, 0, 0, 0);
        if (t > 0) {
          const u16* hp = h0ring + (size_t)((t - 1) & 3) * BHE + arow;
          #pragma unroll
          for (int kk = 0; kk < 16; ++kk) {
            short8 a = *(const short8*)(hp + kk * 32 + q * 8);
            accr = __builtin_amdgcn_mfma_f32_16x16x32_bf16(a, whf[0][kk], accr, 0, 0, 0);
            accz = __builtin_amdgcn_mfma_f32_16x16x32_bf16(a, whf[1][kk], accz, 0, 0, 0);
            ahn  = __builtin_amdgcn_mfma_f32_16x16x32_bf16(a, whf[2][kk], ahn, 0, 0, 0);
          }
        }
        u16* dst = h0ring + (size_t)(t & 3) * BHE;
        #pragma unroll
        for (int r2 = 0; r2 < 4; ++r2) {
          float rr = sigmoidf_(accr[r2] + bi_r + bh_r);
          float zz = sigmoidf_(accz[r2] + bi_z + bh_z);
          float nn = tanhf_(axn[r2] + bi_n + rr * (ahn[r2] + bh_n));
          float hv = (1.0f - zz) * nn + zz * h_old[r2];
          h_old[r2] = hv;
          dst[(size_t)(g * 16 + q * 4 + r2) * 512 + gu] = f2bf(hv);
        }
      }
    } else {
      if (t >= 1) {
        f32x4 accr = {0.f,0.f,0.f,0.f}, accz = {0.f,0.f,0.f,0.f};
        f32x4 axn  = {0.f,0.f,0.f,0.f}, ahn  = {0.f,0.f,0.f,0.f};
        {  // gx1 = Wih1 . h0(t-1)   (B from LDS)
          const u16* hp0 = h0ring + (size_t)((t - 1) & 3) * BHE + arow;
          #pragma unroll
          for (int kk = 0; kk < 16; ++kk) {
            short8 a0 = *(const short8*)(hp0 + kk * 32 + q * 8);
            int bofs = (kk * 64 + q * 16) ^ swz;
            short8 br = *(const short8*)((const char*)Wx1 + (size_t)ul * 1024 + bofs);
            short8 bz = *(const short8*)((const char*)Wx1 + (size_t)(32 + ul) * 1024 + bofs);
            short8 bn = *(const short8*)((const char*)Wx1 + (size_t)(64 + ul) * 1024 + bofs);
            accr = __builtin_amdgcn_mfma_f32_16x16x32_bf16(a0, br, accr, 0, 0, 0);
            accz = __builtin_amdgcn_mfma_f32_16x16x32_bf16(a0, bz, accz, 0, 0, 0);
            axn  = __builtin_amdgcn_mfma_f32_16x16x32_bf16(a0, bn, axn, 0, 0, 0);
          }
        }
        if (t >= 2) {  // gh1 = Whh1 . h1(t-2)  (B from registers)
          const u16* hp1 = h1ring + (size_t)((t - 2) & 3) * BHE + arow;
          #pragma unroll
          for (int kk = 0; kk < 16; ++kk) {
            short8 a1 = *(const short8*)(hp1 + kk * 32 + q * 8);
            accr = __builtin_amdgcn_mfma_f32_16x16x32_bf16(a1, whf[0][kk], accr, 0, 0, 0);
            accz = __builtin_amdgcn_mfma_f32_16x16x32_bf16(a1, whf[1][kk], accz, 0, 0, 0);
            ahn  = __builtin_amdgcn_mfma_f32_16x16x32_bf16(a1, whf[2][kk], ahn, 0, 0, 0);
          }
        }
        u16* dst = h1ring + (size_t)((t - 1) & 3) * BHE;
        #pragma unroll
        for (int r2 = 0; r2 < 4; ++r2) {
          float rr = sigmoidf_(accr[r2] + bi_r + bh_r);
          float zz = sigmoidf_(accz[r2] + bi_z + bh_z);
          float nn = tanhf_(axn[r2] + bi_n + rr * (ahn[r2] + bh_n));
          float hv = (1.0f - zz) * nn + zz * h_old[r2];
          h_old[r2] = hv;
          int row = g * 16 + q * 4 + r2;
          if (t < T_SZ) dst[(size_t)row * 512 + gu] = f2bf(hv);
          else          h1fin[(size_t)row * 512 + gu] = hv;   // h1(255)
        }
      }
    }
    asm volatile("s_waitcnt vmcnt(0)" ::: "memory");  // publishes drained to L2
  }
}

// ---------------- final FC: out[b] = h1[b,:] . w_fc + b_fc ------------------
__global__ __launch_bounds__(256)
void fc_kernel(const float* __restrict__ h, const float* __restrict__ w,
               const float* __restrict__ bfc, float* __restrict__ out) {
  int b = blockIdx.x; int tid = threadIdx.x;
  float s = h[(size_t)b * 512 + tid] * w[tid] + h[(size_t)b * 512 + tid + 256] * w[tid + 256];
  for (int o = 32; o; o >>= 1) s += __shfl_xor(s, o);
  __shared__ float ws4[4];
  if ((tid & 63) == 0) ws4[tid >> 6] = s;
  __syncthreads();
  if (tid == 0) out[b] = ws4[0] + ws4[1] + ws4[2] + ws4[3] + bfc[0];
}

extern "C" void kernel_launch(void* const* d_in, const int* in_sizes, int n_in,
                              void* d_out, int out_size, void* d_ws, size_t ws_size,
                              hipStream_t stream) {
  const float* x     = (const float*)d_in[0];
  const float* v_ih0 = (const float*)d_in[1];
  const float* g_ih0 = (const float*)d_in[2];
  const float* b_ih0 = (const float*)d_in[3];
  const float* v_hh0 = (const float*)d_in[4];
  const float* g_hh0 = (const float*)d_in[5];
  const float* b_hh0 = (const float*)d_in[6];
  const float* v_ih1 = (const float*)d_in[7];
  const float* g_ih1 = (const float*)d_in[8];
  const float* b_ih1 = (const float*)d_in[9];
  const float* v_hh1 = (const float*)d_in[10];
  const float* g_hh1 = (const float*)d_in[11];
  const float* b_hh1 = (const float*)d_in[12];
  const float* w_fc  = (const float*)d_in[13];
  const float* b_fc  = (const float*)d_in[14];
  float* out = (float*)d_out;

  char* w = (char*)d_ws;
  size_t off = 0;
  auto alloc = [&](size_t bytes) -> char* {
    char* p = w + off; off += (bytes + 255) & ~(size_t)255; return p;
  };
  int*   flags  = (int*)alloc(4096 + 256);   // 16 groups x 64-int stride, claim[8]
  int*   claim  = flags + 1024;
  float* h1fin  = (float*)alloc((size_t)256 * 512 * 4);
  u16*   h0ring = (u16*)alloc((size_t)4 * BHE * 2);
  u16*   h1ring = (u16*)alloc((size_t)4 * BHE * 2);
  u16*   xb     = (u16*)alloc((size_t)B_SZ * T_SZ * IN_SZ * 2);
  u16*   wih0   = (u16*)alloc((size_t)G3 * IN_SZ * 2);
  u16*   whh0   = (u16*)alloc((size_t)G3 * H_SZ * 2);
  u16*   wih1   = (u16*)alloc((size_t)G3 * H_SZ * 2);
  u16*   whh1   = (u16*)alloc((size_t)G3 * H_SZ * 2);
  if (off > ws_size) return;  // ~14MB; evidenced ws is far larger

  hipMemsetAsync(flags, 0, 4096 + 256, stream);
  norm_cast_kernel<<<384, 256, 0, stream>>>(v_ih0, g_ih0, wih0, IN_SZ);
  norm_cast_kernel<<<384, 256, 0, stream>>>(v_hh0, g_hh0, whh0, H_SZ);
  norm_cast_kernel<<<384, 256, 0, stream>>>(v_ih1, g_ih1, wih1, H_SZ);
  norm_cast_kernel<<<384, 256, 0, stream>>>(v_hh1, g_hh1, whh1, H_SZ);
  castx_kernel<<<4096, 256, 0, stream>>>(x, xb);

  fused_rnn_kernel<<<256, 256, 0, stream>>>(whh0, wih0, whh1, wih1,
                                            b_ih0, b_hh0, b_ih1, b_hh1,
                                            xb, h0ring, h1ring, h1fin,
                                            flags, claim);
  fc_kernel<<<256, 256, 0, stream>>>(h1fin, w_fc, b_fc, out);
}

// Round 13
// 1352.380 us; speedup vs baseline: 1.3028x; 1.3028x over previous
//
#include <hip/hip_runtime.h>
#include <hip/hip_bf16.h>
#include <cstdint>
#include <cstddef>

typedef unsigned short u16;
typedef __attribute__((ext_vector_type(4))) float f32x4;
typedef __attribute__((ext_vector_type(8))) short short8;

#define B_SZ 256
#define T_SZ 256
#define IN_SZ 64
#define H_SZ 512
#define G3 1536
#define BHE (256 * 512)   // elements per ring slot

__device__ __forceinline__ u16 f2bf(float f) {
  union { float f; unsigned int i; } v; v.f = f;
  unsigned int x = v.i;
  unsigned int r = (x + 0x7fffu + ((x >> 16) & 1u)) >> 16;  // RNE
  return (u16)r;
}
__device__ __forceinline__ float sigmoidf_(float x) { return 1.0f / (1.0f + __expf(-x)); }
__device__ __forceinline__ float tanhf_(float x) {
  float e = __expf(-2.0f * x); return (1.0f - e) / (1.0f + e);
}

// ---------------- weight-norm + bf16 cast: one wave per row ----------------
__global__ __launch_bounds__(256)
void norm_cast_kernel(const float* __restrict__ v, const float* __restrict__ g,
                      u16* __restrict__ out, int cols) {
  int row = blockIdx.x * 4 + (threadIdx.x >> 6);
  int lane = threadIdx.x & 63;
  const float* vr = v + (size_t)row * cols;
  float s = 0.f;
  for (int c = lane; c < cols; c += 64) { float t = vr[c]; s += t * t; }
  for (int o = 32; o; o >>= 1) s += __shfl_xor(s, o);
  float scale = g[row] / sqrtf(s);
  for (int c = lane; c < cols; c += 64) out[(size_t)row * cols + c] = f2bf(vr[c] * scale);
}

__global__ __launch_bounds__(256)
void castx_kernel(const float* __restrict__ x, u16* __restrict__ xb) {
  int i = blockIdx.x * 256 + threadIdx.x;
  float4 v = ((const float4*)x)[i];
  ushort4 o;
  o.x = f2bf(v.x); o.y = f2bf(v.y); o.z = f2bf(v.z); o.w = f2bf(v.w);
  ((ushort4*)xb)[i] = o;
}

// ------------- fused 2-layer GRU: both layers in one block, 1 flag/step -----
// R11 structure + sync mechanism EXACTLY (sc1 atomic flags, wave0-only poll,
// one buffer_inv per step). New this round: all h-ring A-fragments are
// PRELOADED into register arrays before the MFMA chains (16-32 loads in
// flight, one wait) -- converts ~200cyc/load serialized L2 hits into
// overlapped MLP. 1 wave/SIMD => VGPR budget 512, no occupancy cost.
__global__ __launch_bounds__(256, 1)
void fused_rnn_kernel(const u16* __restrict__ whh0c, const u16* __restrict__ wih0c,
                      const u16* __restrict__ whh1c, const u16* __restrict__ wih1c,
                      const float* __restrict__ bih0, const float* __restrict__ bhh0,
                      const float* __restrict__ bih1, const float* __restrict__ bhh1,
                      const u16* __restrict__ xb, u16* __restrict__ h0ring,
                      u16* __restrict__ h1ring, float* __restrict__ h1fin,
                      int* __restrict__ flags, int* __restrict__ claim) {
  __shared__ u16 Wx1[96 * 512];   // Wih1 slice (3x32 gate rows x 512), swizzled
  __shared__ int role_sh;

  const int tid = threadIdx.x;
  if (tid == 0) {
    int xcd;
    asm volatile("s_getreg_b32 %0, hwreg(HW_REG_XCC_ID)" : "=s"(xcd));
    xcd &= 7;
    role_sh = xcd * 64 + atomicAdd(&claim[xcd], 1);
  }
  __syncthreads();
  const int r = role_sh & 63;
  if (r >= 32) return;               // can't happen (pigeonhole 32/XCD)
  const int g = (role_sh >> 6) * 2 + (r & 1);   // batch group (16 rows)
  const int s = r >> 1;              // hidden slice (32 units)

  const int lane = tid & 63;
  const int wv = tid >> 6;
  const int u16i = wv & 1;           // unit-tile within slice
  const int isL1 = wv >> 1;          // layer role
  const int l15 = lane & 15;
  const int q = lane >> 4;
  const int ul = u16i * 16 + l15;    // local unit 0..31
  const int gu = s * 32 + ul;        // global unit
  const int swz = (ul & 7) << 4;
  const size_t arow = (size_t)(g * 16 + l15) * 512;   // A-row base in rings

  // stage Wih1 slice swizzled into LDS
  for (int idx = tid; idx < 6144; idx += 256) {
    int rr = idx >> 6, c16 = idx & 63;
    int grow = (rr >> 5) * 512 + s * 32 + (rr & 31);
    int sb = (c16 << 4) ^ ((rr & 7) << 4);
    uint4 vv = *(const uint4*)((const char*)wih1c + (size_t)grow * 1024 + sb);
    *(uint4*)((char*)Wx1 + rr * 1024 + (c16 << 4)) = vv;
  }

  // Whh fragments -> registers (48 x short8), per layer role
  const u16* whhp = isL1 ? whh1c : whh0c;
  short8 whf[3][16];
  #pragma unroll
  for (int g3 = 0; g3 < 3; ++g3)
    #pragma unroll
    for (int kk = 0; kk < 16; ++kk)
      whf[g3][kk] = *(const short8*)(whhp + (size_t)(g3 * 512 + gu) * 512 + kk * 32 + q * 8);
  // L0: Wih0 fragments
  short8 wxf[3][2];
  if (!isL1) {
    #pragma unroll
    for (int g3 = 0; g3 < 3; ++g3)
      #pragma unroll
      for (int k2 = 0; k2 < 2; ++k2)
        wxf[g3][k2] = *(const short8*)(wih0c + (size_t)(g3 * 512 + gu) * 64 + k2 * 32 + q * 8);
  }
  const float* bi = isL1 ? bih1 : bih0;
  const float* bh = isL1 ? bhh1 : bhh0;
  const float bi_r = bi[gu], bi_z = bi[512 + gu], bi_n = bi[1024 + gu];
  const float bh_r = bh[gu], bh_z = bh[512 + gu], bh_n = bh[1024 + gu];

  __syncthreads();   // staging visible

  int* gf = flags + g * 64;          // this group's 16 flags (one 64B line)
  float h_old[4] = {0.f, 0.f, 0.f, 0.f};

  for (int t = 0; t <= T_SZ; ++t) {
    if (t > 0) {
      __syncthreads();               // all 4 waves' step t-1 publishes drained
      if (wv == 0) {
        if (lane == 0)
          __hip_atomic_store(&gf[s], t, __ATOMIC_RELAXED, __HIP_MEMORY_SCOPE_AGENT);
        int* p = gf + l15;           // 64 lanes poll 16 flags (4x dup)
        int cap = 0;
        while (__hip_atomic_load(p, __ATOMIC_RELAXED, __HIP_MEMORY_SCOPE_AGENT) < t) {
          __builtin_amdgcn_s_sleep(2);
          if (++cap > 200000) break; // hang breaker; never hit in normal runs
        }
        __builtin_amdgcn_sched_barrier(0);
      }
      __syncthreads();               // release all waves
      asm volatile("buffer_inv sc0" ::: "memory");   // once per step
    }
    if (!isL1) {
      if (t < T_SZ) {
        // ---- preload all A-operands (xb + 16 gh0 frags), then MFMA ----
        const u16* xp = xb + ((size_t)(g * 16 + l15) * T_SZ + t) * 64;
        short8 ax0 = *(const short8*)(xp + q * 8);
        short8 ax1 = *(const short8*)(xp + 32 + q * 8);
        short8 af[16];
        if (t > 0) {
          const u16* hp = h0ring + (size_t)((t - 1) & 3) * BHE + arow;
          #pragma unroll
          for (int kk = 0; kk < 16; ++kk)
            af[kk] = *(const short8*)(hp + kk * 32 + q * 8);
        }
        f32x4 accr = {0.f,0.f,0.f,0.f}, accz = {0.f,0.f,0.f,0.f};
        f32x4 axn  = {0.f,0.f,0.f,0.f}, ahn  = {0.f,0.f,0.f,0.f};
        accr = __builtin_amdgcn_mfma_f32_16x16x32_bf16(ax0, wxf[0][0], accr, 0, 0, 0);
        accz = __builtin_amdgcn_mfma_f32_16x16x32_bf16(ax0, wxf[1][0], accz, 0, 0, 0);
        axn  = __builtin_amdgcn_mfma_f32_16x16x32_bf16(ax0, wxf[2][0], axn, 0, 0, 0);
        accr = __builtin_amdgcn_mfma_f32_16x16x32_bf16(ax1, wxf[0][1], accr, 0, 0, 0);
        accz = __builtin_amdgcn_mfma_f32_16x16x32_bf16(ax1, wxf[1][1], accz, 0, 0, 0);
        axn  = __builtin_amdgcn_mfma_f32_16x16x32_bf16(ax1, wxf[2][1], axn, 0, 0, 0);
        if (t > 0) {
          #pragma unroll
          for (int kk = 0; kk < 16; ++kk) {
            accr = __builtin_amdgcn_mfma_f32_16x16x32_bf16(af[kk], whf[0][kk], accr, 0, 0, 0);
            accz = __builtin_amdgcn_mfma_f32_16x16x32_bf16(af[kk], whf[1][kk], accz, 0, 0, 0);
            ahn  = __builtin_amdgcn_mfma_f32_16x16x32_bf16(af[kk], whf[2][kk], ahn, 0, 0, 0);
          }
        }
        u16* dst = h0ring + (size_t)(t & 3) * BHE;
        #pragma unroll
        for (int r2 = 0; r2 < 4; ++r2) {
          float rr = sigmoidf_(accr[r2] + bi_r + bh_r);
          float zz = sigmoidf_(accz[r2] + bi_z + bh_z);
          float nn = tanhf_(axn[r2] + bi_n + rr * (ahn[r2] + bh_n));
          float hv = (1.0f - zz) * nn + zz * h_old[r2];
          h_old[r2] = hv;
          dst[(size_t)(g * 16 + q * 4 + r2) * 512 + gu] = f2bf(hv);
        }
      }
    } else {
      if (t >= 1) {
        // ---- preload all 32 A-frags (gx1 from h0(t-1), gh1 from h1(t-2)) ----
        const u16* hp0 = h0ring + (size_t)((t - 1) & 3) * BHE + arow;
        short8 af0[16];
        #pragma unroll
        for (int kk = 0; kk < 16; ++kk)
          af0[kk] = *(const short8*)(hp0 + kk * 32 + q * 8);
        short8 af1[16];
        if (t >= 2) {
          const u16* hp1 = h1ring + (size_t)((t - 2) & 3) * BHE + arow;
          #pragma unroll
          for (int kk = 0; kk < 16; ++kk)
            af1[kk] = *(const short8*)(hp1 + kk * 32 + q * 8);
        }
        f32x4 accr = {0.f,0.f,0.f,0.f}, accz = {0.f,0.f,0.f,0.f};
        f32x4 axn  = {0.f,0.f,0.f,0.f}, ahn  = {0.f,0.f,0.f,0.f};
        {  // gx1 = Wih1 . h0(t-1)   (B from LDS)
          #pragma unroll
          for (int kk = 0; kk < 16; ++kk) {
            int bofs = (kk * 64 + q * 16) ^ swz;
            short8 br = *(const short8*)((const char*)Wx1 + (size_t)ul * 1024 + bofs);
            short8 bz = *(const short8*)((const char*)Wx1 + (size_t)(32 + ul) * 1024 + bofs);
            short8 bn = *(const short8*)((const char*)Wx1 + (size_t)(64 + ul) * 1024 + bofs);
            accr = __builtin_amdgcn_mfma_f32_16x16x32_bf16(af0[kk], br, accr, 0, 0, 0);
            accz = __builtin_amdgcn_mfma_f32_16x16x32_bf16(af0[kk], bz, accz, 0, 0, 0);
            axn  = __builtin_amdgcn_mfma_f32_16x16x32_bf16(af0[kk], bn, axn, 0, 0, 0);
          }
        }
        if (t >= 2) {  // gh1 = Whh1 . h1(t-2)  (B from registers)
          #pragma unroll
          for (int kk = 0; kk < 16; ++kk) {
            accr = __builtin_amdgcn_mfma_f32_16x16x32_bf16(af1[kk], whf[0][kk], accr, 0, 0, 0);
            accz = __builtin_amdgcn_mfma_f32_16x16x32_bf16(af1[kk], whf[1][kk], accz, 0, 0, 0);
            ahn  = __builtin_amdgcn_mfma_f32_16x16x32_bf16(af1[kk], whf[2][kk], ahn, 0, 0, 0);
          }
        }
        u16* dst = h1ring + (size_t)((t - 1) & 3) * BHE;
        #pragma unroll
        for (int r2 = 0; r2 < 4; ++r2) {
          float rr = sigmoidf_(accr[r2] + bi_r + bh_r);
          float zz = sigmoidf_(accz[r2] + bi_z + bh_z);
          float nn = tanhf_(axn[r2] + bi_n + rr * (ahn[r2] + bh_n));
          float hv = (1.0f - zz) * nn + zz * h_old[r2];
          h_old[r2] = hv;
          int row = g * 16 + q * 4 + r2;
          if (t < T_SZ) dst[(size_t)row * 512 + gu] = f2bf(hv);
          else          h1fin[(size_t)row * 512 + gu] = hv;   // h1(255)
        }
      }
    }
    asm volatile("s_waitcnt vmcnt(0)" ::: "memory");  // publishes drained to L2
  }
}

// ---------------- final FC: out[b] = h1[b,:] . w_fc + b_fc ------------------
__global__ __launch_bounds__(256)
void fc_kernel(const float* __restrict__ h, const float* __restrict__ w,
               const float* __restrict__ bfc, float* __restrict__ out) {
  int b = blockIdx.x; int tid = threadIdx.x;
  float s = h[(size_t)b * 512 + tid] * w[tid] + h[(size_t)b * 512 + tid + 256] * w[tid + 256];
  for (int o = 32; o; o >>= 1) s += __shfl_xor(s, o);
  __shared__ float ws4[4];
  if ((tid & 63) == 0) ws4[tid >> 6] = s;
  __syncthreads();
  if (tid == 0) out[b] = ws4[0] + ws4[1] + ws4[2] + ws4[3] + bfc[0];
}

extern "C" void kernel_launch(void* const* d_in, const int* in_sizes, int n_in,
                              void* d_out, int out_size, void* d_ws, size_t ws_size,
                              hipStream_t stream) {
  const float* x     = (const float*)d_in[0];
  const float* v_ih0 = (const float*)d_in[1];
  const float* g_ih0 = (const float*)d_in[2];
  const float* b_ih0 = (const float*)d_in[3];
  const float* v_hh0 = (const float*)d_in[4];
  const float* g_hh0 = (const float*)d_in[5];
  const float* b_hh0 = (const float*)d_in[6];
  const float* v_ih1 = (const float*)d_in[7];
  const float* g_ih1 = (const float*)d_in[8];
  const float* b_ih1 = (const float*)d_in[9];
  const float* v_hh1 = (const float*)d_in[10];
  const float* g_hh1 = (const float*)d_in[11];
  const float* b_hh1 = (const float*)d_in[12];
  const float* w_fc  = (const float*)d_in[13];
  const float* b_fc  = (const float*)d_in[14];
  float* out = (float*)d_out;

  char* w = (char*)d_ws;
  size_t off = 0;
  auto alloc = [&](size_t bytes) -> char* {
    char* p = w + off; off += (bytes + 255) & ~(size_t)255; return p;
  };
  int*   flags  = (int*)alloc(4096 + 256);   // 16 groups x 64-int stride, claim[8]
  int*   claim  = flags + 1024;
  float* h1fin  = (float*)alloc((size_t)256 * 512 * 4);
  u16*   h0ring = (u16*)alloc((size_t)4 * BHE * 2);
  u16*   h1ring = (u16*)alloc((size_t)4 * BHE * 2);
  u16*   xb     = (u16*)alloc((size_t)B_SZ * T_SZ * IN_SZ * 2);
  u16*   wih0   = (u16*)alloc((size_t)G3 * IN_SZ * 2);
  u16*   whh0   = (u16*)alloc((size_t)G3 * H_SZ * 2);
  u16*   wih1   = (u16*)alloc((size_t)G3 * H_SZ * 2);
  u16*   whh1   = (u16*)alloc((size_t)G3 * H_SZ * 2);
  if (off > ws_size) return;  // ~14MB; evidenced ws is far larger

  hipMemsetAsync(flags, 0, 4096 + 256, stream);
  norm_cast_kernel<<<384, 256, 0, stream>>>(v_ih0, g_ih0, wih0, IN_SZ);
  norm_cast_kernel<<<384, 256, 0, stream>>>(v_hh0, g_hh0, whh0, H_SZ);
  norm_cast_kernel<<<384, 256, 0, stream>>>(v_ih1, g_ih1, wih1, H_SZ);
  norm_cast_kernel<<<384, 256, 0, stream>>>(v_hh1, g_hh1, whh1, H_SZ);
  castx_kernel<<<4096, 256, 0, stream>>>(x, xb);

  fused_rnn_kernel<<<256, 256, 0, stream>>>(whh0, wih0, whh1, wih1,
                                            b_ih0, b_hh0, b_ih1, b_hh1,
                                            xb, h0ring, h1ring, h1fin,
                                            flags, claim);
  fc_kernel<<<256, 256, 0, stream>>>(h1fin, w_fc, b_fc, out);
}